// Round 2
// baseline (790.379 us; speedup 1.0000x reference)
//
#include <hip/hip_runtime.h>
#include <hip/hip_bf16.h>

// Problem constants
#define B_    128
#define G_    10000
#define KW_   20
#define C_    3
#define LAT_  2000
#define GC_   30000      // G*C
#define INLEN_ 200000    // N_LOCI*2

typedef short bf16x8 __attribute__((ext_vector_type(8)));
typedef float f32x4  __attribute__((ext_vector_type(4)));

__device__ __forceinline__ float leaky(float x) { return x >= 0.f ? x : 0.1f * x; }

__device__ __forceinline__ unsigned short f2bf(float f) {
    union { float f; unsigned u; } v; v.f = f;
    unsigned r = v.u + 0x7fffu + ((v.u >> 16) & 1u);   // RNE
    return (unsigned short)(r >> 16);
}
__device__ __forceinline__ float bf2f(unsigned short u) {
    union { unsigned u; float f; } v; v.u = ((unsigned)u) << 16; return v.f;
}
// packed fp32x2 -> bf16x2 (RNE) via HIP intrinsic
__device__ __forceinline__ unsigned pk2(float x, float y) {
    __hip_bfloat162 h = __float22bfloat162_rn(make_float2(x, y));
    union { __hip_bfloat162 b; unsigned u; } c; c.b = h; return c.u;
}

// ---------------------------------------------------------------------------
// Kernel 1: encoder grouped conv (no LDS: per-thread rows are cache-line clean)
// ---------------------------------------------------------------------------
__global__ __launch_bounds__(256) void k_enc(const float* __restrict__ x,
                                             const float* __restrict__ w,
                                             const float* __restrict__ bias,
                                             unsigned short* __restrict__ h) {
    const int g = blockIdx.x * 256 + threadIdx.x;
    const int b = blockIdx.y;
    if (g >= G_) return;

    float xr[20];
    const float4* x4 = (const float4*)(x + (size_t)b * INLEN_ + g * KW_);
    #pragma unroll
    for (int i = 0; i < 5; ++i) {
        float4 v = x4[i];
        xr[4*i] = v.x; xr[4*i+1] = v.y; xr[4*i+2] = v.z; xr[4*i+3] = v.w;
    }
    float wl[60];
    const float4* w4 = (const float4*)(w + (size_t)g * 60);
    #pragma unroll
    for (int i = 0; i < 15; ++i) {
        float4 v = w4[i];
        wl[4*i] = v.x; wl[4*i+1] = v.y; wl[4*i+2] = v.z; wl[4*i+3] = v.w;
    }
    unsigned short* hp = h + (size_t)b * GC_ + g * C_;
    #pragma unroll
    for (int c = 0; c < C_; ++c) {
        float s = bias[g * C_ + c];
        #pragma unroll
        for (int k = 0; k < KW_; ++k) s += xr[k] * wl[c * KW_ + k];
        hp[c] = f2bf(leaky(s));
    }
}

// ---------------------------------------------------------------------------
// FC GEMM, LDS-free / barrier-free. C[m,n] = sum_k A[m,k]*W[n,k], M=128.
// One wave owns a 64x64 tile (4x4 frags of 16x16x32 bf16). A bf16 / W fp32
// loaded straight into MFMA fragment layout; fp32->bf16 packed convert in reg.
// Register double-buffer pipeline, no __syncthreads anywhere.
// MODE 0: fp32 partial for split-K chunk kc -> outp.  MODE 1: bias+leaky bf16 -> outb.
// ---------------------------------------------------------------------------
template <int MODE>
__global__ __launch_bounds__(256, 2) void k_fc(const unsigned short* __restrict__ A,
                                               const float* __restrict__ W,
                                               const float* __restrict__ bias,
                                               float* __restrict__ outp,
                                               unsigned short* __restrict__ outb,
                                               int N, int K, int NT, int NC) {
    const int lane = threadIdx.x & 63;
    const int gw   = blockIdx.x * 4 + (threadIdx.x >> 6);
    if (gw >= 2 * NT * NC) return;
    const int kc  = gw / (2 * NT);
    const int rem = gw - kc * 2 * NT;
    const int mt  = rem / NT;
    const int m0  = mt * 64;
    const int n0  = (rem - mt * NT) * 64;
    // 16-aligned K-chunk [kb, ke)
    const int T  = K >> 4;
    const int kb = ((kc * T) / NC) << 4;
    const int ke = (((kc + 1) * T) / NC) << 4;

    const int quad = lane >> 4, l16 = lane & 15;

    const unsigned short* Ap[4];
    const float* Wp[4];
    #pragma unroll
    for (int i = 0; i < 4; ++i) {
        Ap[i] = A + (size_t)(m0 + i * 16 + l16) * K + (kb + quad * 8);
        int r = n0 + i * 16 + l16; if (r >= N) r = N - 1;   // clamp, results discarded
        Wp[i] = W + (size_t)r * K + (kb + quad * 8);
    }

    f32x4 acc[4][4];
    #pragma unroll
    for (int i = 0; i < 4; ++i)
        #pragma unroll
        for (int j = 0; j < 4; ++j) acc[i][j] = (f32x4){0.f, 0.f, 0.f, 0.f};

    uint4 A0[4], A1[4], W0[4][2], W1[4][2];

#define LOADT(Ax, Wx, KOFF)                                              \
    {   _Pragma("unroll")                                                \
        for (int i = 0; i < 4; ++i) {                                    \
            Ax[i] = *(const uint4*)(Ap[i] + (KOFF));                     \
            const uint4* p = (const uint4*)(Wp[i] + (KOFF));             \
            Wx[i][0] = p[0]; Wx[i][1] = p[1];                            \
        }                                                                \
    }

#define COMPT(Ax, Wx)                                                    \
    {   bf16x8 bfr[4];                                                   \
        _Pragma("unroll")                                                \
        for (int ni = 0; ni < 4; ++ni) {                                 \
            union { uint4 u; float4 f; } c0, c1;                         \
            c0.u = Wx[ni][0]; c1.u = Wx[ni][1];                          \
            union { unsigned u[4]; bf16x8 v; } pk;                       \
            pk.u[0] = pk2(c0.f.x, c0.f.y); pk.u[1] = pk2(c0.f.z, c0.f.w);\
            pk.u[2] = pk2(c1.f.x, c1.f.y); pk.u[3] = pk2(c1.f.z, c1.f.w);\
            bfr[ni] = pk.v;                                              \
        }                                                                \
        _Pragma("unroll")                                                \
        for (int mi = 0; mi < 4; ++mi) {                                 \
            union { uint4 u; bf16x8 v; } af; af.u = Ax[mi];              \
            _Pragma("unroll")                                            \
            for (int ni = 0; ni < 4; ++ni)                               \
                acc[mi][ni] = __builtin_amdgcn_mfma_f32_16x16x32_bf16(   \
                    af.v, bfr[ni], acc[mi][ni], 0, 0, 0);                \
        }                                                                \
    }

    const int span = ke - kb;
    const int nf = span >> 5;          // full 32-wide steps
    int ko = 0;
    if (nf > 0) LOADT(A0, W0, 0);
    int it = 0;
    for (; it + 2 <= nf; it += 2) {
        LOADT(A1, W1, ko + 32);
        COMPT(A0, W0);
        if (it + 3 <= nf) LOADT(A0, W0, ko + 64);
        COMPT(A1, W1);
        ko += 64;
    }
    if (it < nf) { COMPT(A0, W0); ko += 32; }
    if (span & 16) {                   // 16-wide tail: quads 2,3 are out of range
        if (quad < 2) { LOADT(A0, W0, ko); }
        else {
            #pragma unroll
            for (int i = 0; i < 4; ++i) {
                A0[i] = make_uint4(0, 0, 0, 0);
                W0[i][0] = make_uint4(0, 0, 0, 0);
                W0[i][1] = make_uint4(0, 0, 0, 0);
            }
        }
        COMPT(A0, W0);
    }
#undef LOADT
#undef COMPT

    // epilogue: D row = quad*4 + r, col = l16 (within each 16x16 frag)
    #pragma unroll
    for (int mi = 0; mi < 4; ++mi) {
        const int row = m0 + mi * 16 + quad * 4;
        #pragma unroll
        for (int ni = 0; ni < 4; ++ni) {
            const int col = n0 + ni * 16 + l16;
            if (col < N) {
                if (MODE == 0) {
                    float* op = outp + (size_t)kc * 128 * N;
                    #pragma unroll
                    for (int r = 0; r < 4; ++r)
                        op[(size_t)(row + r) * N + col] = acc[mi][ni][r];
                } else {
                    const float bv = bias[col];
                    #pragma unroll
                    for (int r = 0; r < 4; ++r)
                        outb[(size_t)(row + r) * N + col] = f2bf(leaky(acc[mi][ni][r] + bv));
                }
            }
        }
    }
}

// ---------------------------------------------------------------------------
// Split-K partial reduction + bias + leaky -> bf16 [128 x N]
// ---------------------------------------------------------------------------
__global__ __launch_bounds__(256) void k_red(const float* __restrict__ zp,
                                             const float* __restrict__ bias,
                                             unsigned short* __restrict__ z,
                                             int N, int NC) {
    const int i = blockIdx.x * 256 + threadIdx.x;
    if (i >= 128 * N) return;
    float s = bias[i - (i / N) * N];
    for (int c = 0; c < NC; ++c) s += zp[(size_t)c * 128 * N + i];
    z[i] = f2bf(leaky(s));
}

// ---------------------------------------------------------------------------
// Decoder conv-transpose + sigmoid
// ---------------------------------------------------------------------------
__global__ __launch_bounds__(256) void k_dec(const unsigned short* __restrict__ d,
                                             const float* __restrict__ w,
                                             const float* __restrict__ bias,
                                             float* __restrict__ out) {
    const int g = blockIdx.x * 256 + threadIdx.x;
    const int b = blockIdx.y;
    if (g >= G_) return;

    const unsigned short* dp = d + (size_t)b * GC_ + g * C_;
    float dv0 = bf2f(dp[0]), dv1 = bf2f(dp[1]), dv2 = bf2f(dp[2]);

    float wl[60];
    const float4* w4 = (const float4*)(w + (size_t)g * 60);
    #pragma unroll
    for (int i = 0; i < 15; ++i) {
        float4 v = w4[i];
        wl[4*i] = v.x; wl[4*i+1] = v.y; wl[4*i+2] = v.z; wl[4*i+3] = v.w;
    }
    const float bg = bias[g];
    float o[20];
    #pragma unroll
    for (int k = 0; k < KW_; ++k) {
        float s = bg + dv0 * wl[k] + dv1 * wl[20 + k] + dv2 * wl[40 + k];
        o[k] = 1.f / (1.f + __expf(-s));
    }
    float4* op = (float4*)(out + (size_t)b * INLEN_ + g * KW_);
    #pragma unroll
    for (int i = 0; i < 5; ++i)
        op[i] = make_float4(o[4*i], o[4*i+1], o[4*i+2], o[4*i+3]);
}

// ---------------------------------------------------------------------------
extern "C" void kernel_launch(void* const* d_in, const int* in_sizes, int n_in,
                              void* d_out, int out_size, void* d_ws, size_t ws_size,
                              hipStream_t stream) {
    const float* x        = (const float*)d_in[0];
    const float* enc_w    = (const float*)d_in[1];
    const float* enc_b    = (const float*)d_in[2];
    const float* enc_fc_w = (const float*)d_in[3];
    const float* enc_fc_b = (const float*)d_in[4];
    const float* dec_fc_w = (const float*)d_in[5];
    const float* dec_fc_b = (const float*)d_in[6];
    const float* dec_w    = (const float*)d_in[7];
    const float* dec_b    = (const float*)d_in[8];
    float* out = (float*)d_out;

    // ws layout (adaptive split-K to fit ws_size; deterministic every call)
    const size_t hB = 7680000, zB = 512000, ddB = 7680000;
    const size_t zp1unit = (size_t)128 * LAT_ * 4;   // 1,024,000 per chunk
    const size_t zp2unit = (size_t)128 * GC_ * 4;    // 15,360,000 per chunk
    int NC1 = 32, NC2 = 2;
    if (ws_size < hB + zB + ddB + 32 * zp1unit + 2 * zp2unit) {
        NC2 = 1;
        size_t avail = (ws_size > hB + zB + ddB) ? ws_size - (hB + zB + ddB) : zp1unit;
        NC1 = (int)(avail / zp1unit);
        if (NC1 > 32) NC1 = 32;
        if (NC1 < 1) NC1 = 1;
    }
    char* ws = (char*)d_ws;
    unsigned short* h   = (unsigned short*)ws;
    float*          zp1 = (float*)(ws + hB);
    unsigned short* z   = (unsigned short*)(ws + hB + NC1 * zp1unit);
    float*          zp2 = (float*)((char*)z + zB);
    unsigned short* dd  = (NC2 == 2) ? (unsigned short*)((char*)zp2 + 2 * zp2unit)
                                     : (unsigned short*)((char*)z + zB);

    k_enc<<<dim3(40, 128), 256, 0, stream>>>(x, enc_w, enc_b, h);

    // FC1: N=2000 (NT=32 tiles of 64), K=30000 split NC1 ways
    {
        int waves = 2 * 32 * NC1;
        k_fc<0><<<dim3((waves + 3) / 4), 256, 0, stream>>>(h, enc_fc_w, nullptr, zp1, nullptr,
                                                           LAT_, GC_, 32, NC1);
        k_red<<<dim3((128 * LAT_ + 255) / 256), 256, 0, stream>>>(zp1, enc_fc_b, z, LAT_, NC1);
    }

    // FC2: N=30000 (NT=469), K=2000
    if (NC2 == 2) {
        int waves = 2 * 469 * 2;
        k_fc<0><<<dim3((waves + 3) / 4), 256, 0, stream>>>(z, dec_fc_w, nullptr, zp2, nullptr,
                                                           GC_, LAT_, 469, 2);
        k_red<<<dim3((128 * GC_ + 255) / 256), 256, 0, stream>>>(zp2, dec_fc_b, dd, GC_, 2);
    } else {
        int waves = 2 * 469;
        k_fc<1><<<dim3((waves + 3) / 4), 256, 0, stream>>>(z, dec_fc_w, dec_fc_b, nullptr, dd,
                                                           GC_, LAT_, 469, 1);
    }

    k_dec<<<dim3(40, 128), 256, 0, stream>>>(dd, dec_w, dec_b, out);
}